// Round 6
// baseline (757.260 us; speedup 1.0000x reference)
//
#include <hip/hip_runtime.h>

// CompressiveMemory — round 6.
//  * gemm_qkv: half-tile (64-row) bf16 epilogue through LDS -> pool 33.8 KB
//    -> 16.9 KB. Occupancy was the limiter (31%, MfmaUtil 21.6%, nothing
//    else busy): now VGPR-capped ~7 blocks/CU (~87%) so the barrier drain
//    hides behind other blocks' waves.
//  * out-GEMM: plain bf16, 1 MFMA (was 3-MFMA split). Error budget:
//    sqrt(K)*|att*W|*2^-8 ~= 1.3e-4 RMS -> predicted absmax 5-8e-4 < 1.29e-3.
//    atl/wol buffers deleted; attn epilogue writes hi only.
//  * attn unchanged from round 5.
// View insight (unchanged): each (b,seg,h) (512x64) tile is the CONTIGUOUS
// 32x1024 row-block at row b*8192+seg*512+h*32; output reshape is inverse.
// z is rank-degenerate; mem is an exclusive prefix of M_seg = sk^T v.

#define H_ 16
#define SEG_ 512
#define NSEG_ 16
#define B_ 2
#define T_ 8192
#define D_ 1024
#define BT_ 16384

#define NPROJ ((size_t)BT_ * D_)   // 16,777,216
#define NW ((size_t)D_ * D_)       // 1,048,576

__device__ unsigned short g_qb[NPROJ], g_kb[NPROJ], g_vb[NPROJ];   // bf16 projections
__device__ unsigned short g_xh[NPROJ];
__device__ unsigned short g_wqkv[3 * NW];                          // [Wq;Wk;Wv] bf16
__device__ unsigned short g_ath[NPROJ];                            // att bf16
__device__ unsigned short g_woh[NW];                               // Wout bf16
__device__ unsigned short g_vt[(size_t)512 * 64 * 512];            // per-tile V^T bf16
__device__ float g_M[(size_t)512 * 4096];
__device__ float g_z[(size_t)512 * 64];

typedef __attribute__((ext_vector_type(8))) short short8;
typedef __attribute__((ext_vector_type(8))) unsigned short ushort8;
typedef __attribute__((ext_vector_type(4))) float f32x4;

__device__ __forceinline__ float elu1(float x) {
    return x > 0.f ? x + 1.f : __expf(x);
}
__device__ __forceinline__ unsigned short f2bf(float x) {
    unsigned u = __float_as_uint(x);
    u += 0x7fffu + ((u >> 16) & 1u);           // RNE
    return (unsigned short)(u >> 16);
}
__device__ __forceinline__ float bf2f(unsigned short h) {
    return __uint_as_float((unsigned)h << 16);
}
__device__ __forceinline__ void load_lds16(const unsigned short* g, unsigned short* l) {
    __builtin_amdgcn_global_load_lds(
        (const __attribute__((address_space(1))) unsigned int*)g,
        (__attribute__((address_space(3))) unsigned int*)l, 16, 0, 0);
}
// ushort offset of (row, 8-elem block) in a [128][32]-bf16 LDS tile, XOR-swizzled.
__device__ __forceinline__ int swz(int row, int blk) {
    return row * 32 + ((blk ^ ((row >> 1) & 3)) << 3);
}

__global__ __launch_bounds__(256) void cast_bf16(
    const float* __restrict__ in, unsigned short* __restrict__ out, int n)
{
    int i = (blockIdx.x * 256 + threadIdx.x) * 4;
    if (i >= n) return;
    float4 x = *(const float4*)(in + i);
    ushort4 h;
    h.x = f2bf(x.x); h.y = f2bf(x.y); h.z = f2bf(x.z); h.w = f2bf(x.w);
    *(ushort4*)(out + i) = h;
}

// Fused QKV: C[m,n] = sum_k x[m,k] * Wqkv[n,k]; n in [0,3072); bf16 out.
// 128x128 tile, BK=32, 4 waves. Epilogue in two 64-row passes (small LDS).
#define BK 32
__global__ __launch_bounds__(256) void gemm_qkv(
    const unsigned short* __restrict__ A, const unsigned short* __restrict__ Bw,
    unsigned short* __restrict__ Q, unsigned short* __restrict__ Kp,
    unsigned short* __restrict__ V)
{
    __shared__ unsigned short pool[64 * 132];    // 16.9 KB: staging(16KB) / epi half-tile
    unsigned short* sA = pool;
    unsigned short* sB = pool + 128 * BK / 1;    // 4096 shorts each
    sB = pool + 4096;
    const int t = threadIdx.x, lane = t & 63, wave = t >> 6;
    const int m0 = blockIdx.y * 128, n0 = blockIdx.x * 128;
    const int wm = (wave & 1) * 64, wn = (wave >> 1) * 64;
    const int srow = wave * 32 + (lane >> 2);
    const int scol = ((lane & 3) ^ ((lane >> 3) & 3)) * 8;   // swizzled fetch col
    const int fr = lane & 15, g4 = lane >> 4;

    f32x4 acc[4][4];
#pragma unroll
    for (int i = 0; i < 4; ++i)
#pragma unroll
        for (int j = 0; j < 4; ++j) acc[i][j] = (f32x4)0.f;

    for (int k0 = 0; k0 < D_; k0 += BK) {
        __syncthreads();
#pragma unroll
        for (int i = 0; i < 2; ++i) {
            const size_t ga = (size_t)(m0 + srow + i * 16) * D_ + k0 + scol;
            const size_t gb = (size_t)(n0 + srow + i * 16) * D_ + k0 + scol;
            const int lb = (wave * 32 + i * 16) * BK;
            load_lds16(A + ga, &sA[lb]);
            load_lds16(Bw + gb, &sB[lb]);
        }
        __syncthreads();
        short8 a[4], b[4];
#pragma unroll
        for (int i = 0; i < 4; ++i) a[i] = *(const short8*)&sA[swz(wm + i * 16 + fr, g4)];
#pragma unroll
        for (int j = 0; j < 4; ++j) b[j] = *(const short8*)&sB[swz(wn + j * 16 + fr, g4)];
#pragma unroll
        for (int i = 0; i < 4; ++i)
#pragma unroll
            for (int j = 0; j < 4; ++j)
                acc[i][j] = __builtin_amdgcn_mfma_f32_16x16x32_bf16(a[i], b[j], acc[i][j], 0, 0, 0);
    }

    const int which = n0 >> 10, col0 = n0 & 1023;
    unsigned short* outp = which == 0 ? Q : (which == 1 ? Kp : V);
    const int ccol = lane & 15, crow = (lane >> 4) * 4;
    const int cprow = t >> 2, cpch = (t & 3) * 32;   // copy-out: 64 rows x 128 cols
#pragma unroll
    for (int half = 0; half < 2; ++half) {
        __syncthreads();
        if ((wave & 1) == half) {
#pragma unroll
            for (int i = 0; i < 4; ++i)
#pragma unroll
                for (int j = 0; j < 4; ++j)
#pragma unroll
                    for (int r = 0; r < 4; ++r)
                        pool[(i * 16 + crow + r) * 132 + wn + j * 16 + ccol] = f2bf(acc[i][j][r]);
        }
        __syncthreads();
        unsigned short* gp = outp + (size_t)(m0 + half * 64 + cprow) * D_ + col0 + cpch;
        const unsigned short* lp = &pool[cprow * 132 + cpch];
#pragma unroll
        for (int u = 0; u < 32; u += 8)
            *(ushort8*)(gp + u) = *(const ushort8*)(lp + u);
    }
}

// Out-GEMM: C[m,n] = sum_k A[m,k]*B[n,k], plain bf16 (1 MFMA), fp32 C.
__global__ __launch_bounds__(256) void gemm_bt_bf16(
    const unsigned short* __restrict__ Ah, const unsigned short* __restrict__ Bh,
    float* __restrict__ C, int M, int N, int K)
{
    __shared__ unsigned short sA[128 * BK];
    __shared__ unsigned short sB[128 * BK];
    const int t = threadIdx.x, lane = t & 63, wave = t >> 6;
    const int m0 = blockIdx.y * 128, n0 = blockIdx.x * 128;
    const int wm = (wave & 1) * 64, wn = (wave >> 1) * 64;
    const int srow = wave * 32 + (lane >> 2);
    const int scol = ((lane & 3) ^ ((lane >> 3) & 3)) * 8;
    const int fr = lane & 15, g4 = lane >> 4;

    f32x4 acc[4][4];
#pragma unroll
    for (int i = 0; i < 4; ++i)
#pragma unroll
        for (int j = 0; j < 4; ++j) acc[i][j] = (f32x4)0.f;

    for (int k0 = 0; k0 < K; k0 += BK) {
        __syncthreads();
#pragma unroll
        for (int i = 0; i < 2; ++i) {
            const size_t ga = (size_t)(m0 + srow + i * 16) * K + k0 + scol;
            const size_t gb = (size_t)(n0 + srow + i * 16) * K + k0 + scol;
            const int lb = (wave * 32 + i * 16) * BK;
            load_lds16(Ah + ga, &sA[lb]);
            load_lds16(Bh + gb, &sB[lb]);
        }
        __syncthreads();
        short8 a[4], b[4];
#pragma unroll
        for (int i = 0; i < 4; ++i) a[i] = *(const short8*)&sA[swz(wm + i * 16 + fr, g4)];
#pragma unroll
        for (int j = 0; j < 4; ++j) b[j] = *(const short8*)&sB[swz(wn + j * 16 + fr, g4)];
#pragma unroll
        for (int i = 0; i < 4; ++i)
#pragma unroll
            for (int j = 0; j < 4; ++j)
                acc[i][j] = __builtin_amdgcn_mfma_f32_16x16x32_bf16(a[i], b[j], acc[i][j], 0, 0, 0);
    }
    const int ccol = lane & 15, crow = (lane >> 4) * 4;
#pragma unroll
    for (int i = 0; i < 4; ++i)
#pragma unroll
        for (int j = 0; j < 4; ++j) {
            float* cp = C + (size_t)(m0 + wm + i * 16 + crow) * N + (n0 + wn + j * 16 + ccol);
#pragma unroll
            for (int r = 0; r < 4; ++r) cp[(size_t)r * N] = acc[i][j][r];
        }
}

// Per (b,h,seg): M_seg[d][v], zsum[d], and V^T bf16 tile. Inputs bf16.
__global__ __launch_bounds__(256) void seg_stats(
    const unsigned short* __restrict__ kproj, const unsigned short* __restrict__ vproj,
    float* __restrict__ Mseg, float* __restrict__ zsum,
    unsigned short* __restrict__ vtg)
{
    __shared__ float ks[64][68];
    __shared__ float vs[64][68];
    const int idx = blockIdx.x;
    const int seg = idx & 15;
    const int bh  = idx >> 4;
    const int h   = bh & 15;
    const int b   = bh >> 4;
    const size_t base = ((size_t)b * T_ + (size_t)seg * SEG_ + (size_t)h * 32) * D_;
    const unsigned short* kt = kproj + base;
    const unsigned short* vt = vproj + base;
    const int t  = threadIdx.x;
    const int d0 = (t >> 4) * 4;
    const int v0 = (t & 15) * 4;
    const int lr = t >> 2;
    const int lc = (t & 3) * 16;
    float acc[4][4];
#pragma unroll
    for (int i = 0; i < 4; ++i)
#pragma unroll
        for (int j = 0; j < 4; ++j) acc[i][j] = 0.f;
    float zacc = 0.f;

    for (int c0 = 0; c0 < SEG_; c0 += 64) {
        __syncthreads();
        {
            const unsigned short* kp = kt + (size_t)(c0 + lr) * 64 + lc;
            const unsigned short* vp = vt + (size_t)(c0 + lr) * 64 + lc;
            ushort8 k0 = *(const ushort8*)kp,  k1 = *(const ushort8*)(kp + 8);
            ushort8 v0v = *(const ushort8*)vp, v1 = *(const ushort8*)(vp + 8);
#pragma unroll
            for (int e = 0; e < 8; ++e) {
                ks[lr][lc + e]     = elu1(bf2f(k0[e]));
                ks[lr][lc + 8 + e] = elu1(bf2f(k1[e]));
                vs[lr][lc + e]     = bf2f(v0v[e]);
                vs[lr][lc + 8 + e] = bf2f(v1[e]);
            }
        }
        __syncthreads();
#pragma unroll 8
        for (int i = 0; i < 64; ++i) {
            float a0 = ks[i][d0 + 0], a1 = ks[i][d0 + 1];
            float a2 = ks[i][d0 + 2], a3 = ks[i][d0 + 3];
            float b0 = vs[i][v0 + 0], b1 = vs[i][v0 + 1];
            float b2 = vs[i][v0 + 2], b3 = vs[i][v0 + 3];
            acc[0][0] += a0 * b0; acc[0][1] += a0 * b1; acc[0][2] += a0 * b2; acc[0][3] += a0 * b3;
            acc[1][0] += a1 * b0; acc[1][1] += a1 * b1; acc[1][2] += a1 * b2; acc[1][3] += a1 * b3;
            acc[2][0] += a2 * b0; acc[2][1] += a2 * b1; acc[2][2] += a2 * b2; acc[2][3] += a2 * b3;
            acc[3][0] += a3 * b0; acc[3][1] += a3 * b1; acc[3][2] += a3 * b2; acc[3][3] += a3 * b3;
        }
        if (t < 64) {
#pragma unroll 8
            for (int i = 0; i < 64; ++i) zacc += ks[i][t];
        }
        {   // V^T bf16: row = v-dim (lr), cols = time
            ushort8 w0, w1;
#pragma unroll
            for (int i = 0; i < 8; ++i) w0[i] = f2bf(vs[lc + i][lr]);
#pragma unroll
            for (int i = 0; i < 8; ++i) w1[i] = f2bf(vs[lc + 8 + i][lr]);
            unsigned short* vo = vtg + ((size_t)idx * 64 + lr) * 512 + c0 + lc;
            *(ushort8*)vo       = w0;
            *(ushort8*)(vo + 8) = w1;
        }
    }
    float* Mout = Mseg + (size_t)idx * 4096;
#pragma unroll
    for (int i = 0; i < 4; ++i)
        *(float4*)(Mout + (size_t)(d0 + i) * 64 + v0) =
            make_float4(acc[i][0], acc[i][1], acc[i][2], acc[i][3]);
    if (t < 64) zsum[(size_t)idx * 64 + t] = zacc;
}

// Per (b,h): in-place exclusive prefix of M, inclusive prefix of z.
__global__ __launch_bounds__(256) void prefix_scan(
    float* __restrict__ M, float* __restrict__ z)
{
    const int bh = blockIdx.x;
    const int t  = threadIdx.x;
    float run[16];
#pragma unroll
    for (int u = 0; u < 16; ++u) run[u] = 0.f;
    float runz = 0.f;
    for (int seg = 0; seg < NSEG_; ++seg) {
        const size_t o = ((size_t)bh * NSEG_ + seg) * 4096 + (size_t)t * 16;
#pragma unroll
        for (int u = 0; u < 16; u += 4) {
            float4 m = *(const float4*)(M + o + u);
            *(float4*)(M + o + u) = make_float4(run[u], run[u+1], run[u+2], run[u+3]);
            run[u] += m.x; run[u+1] += m.y; run[u+2] += m.z; run[u+3] += m.w;
        }
        if (t < 64) {
            const size_t oz = ((size_t)bh * NSEG_ + seg) * 64 + t;
            runz += z[oz];
            z[oz] = runz;
        }
    }
}

// MFMA flash attention per (b,h,seg,64-row q-chunk). bf16 q/k/v inputs.
__global__ __launch_bounds__(256) void attn_mfma(
    const unsigned short* __restrict__ qproj, const unsigned short* __restrict__ kproj,
    const unsigned short* __restrict__ vtg, const float* __restrict__ memb,
    const float* __restrict__ Zaf, const float* __restrict__ betas,
    unsigned short* __restrict__ ath)
{
    __shared__ unsigned short sm_k[64 * 72];   // k bf16 ; epilogue att
    __shared__ unsigned short sm_v[64 * 72];   // V^T bf16
    __shared__ unsigned short sm_p[64 * 72];   // mem^T bf16, then P bf16
    __shared__ float Zsh[64], gsh[64];

    const int idx  = blockIdx.x;
    const int qc   = idx & 7;
    const int rest = idx >> 3;
    const int h    = (rest >> 4) & 15;
    const int b    = rest >> 8;
    const int seg  = rest & 15;
    const size_t base = ((size_t)b * T_ + (size_t)seg * SEG_ + (size_t)h * 32) * D_;

    const int t    = threadIdx.x;
    const int lane = t & 63;
    const int w    = t >> 6;
    const int c16  = lane & 15;
    const int g4   = lane >> 4;
    const int lr   = t >> 2;
    const int lc   = (t & 3) * 16;

    const unsigned short* qt = qproj + base + (size_t)qc * 4096;
    const unsigned short* kt = kproj + base;
    const unsigned short* vt = vtg + (size_t)rest * (64 * 512);
    const float* mb = memb + (size_t)rest * 4096;

    if (t < 64) {
        Zsh[t] = Zaf[(size_t)rest * 64 + t];
        gsh[t] = 1.f / (1.f + __expf(-betas[h * 64 + t]));
    }

    // q fragments (A-layout: m = w*16+c16, k = g4*8 + ks*32 + j), sq, rowsum
    short8 qh[2], sqh[2];
    float rowsum = 0.f;
#pragma unroll
    for (int ks = 0; ks < 2; ++ks) {
        const unsigned short* qp = qt + (size_t)(w * 16 + c16) * 64 + g4 * 8 + ks * 32;
        ushort8 qv = *(const ushort8*)qp;
        short8 qf, sf;
#pragma unroll
        for (int j = 0; j < 8; ++j) {
            float e = elu1(bf2f(qv[j]));
            rowsum += e;
            qf[j] = (short)qv[j];
            sf[j] = (short)f2bf(e);
        }
        qh[ks] = qf; sqh[ks] = sf;
    }
    rowsum += __shfl_xor(rowsum, 16);
    rowsum += __shfl_xor(rowsum, 32);

    // stage mem^T (bf16) into sm_p
    {
        const float* mp = mb + (size_t)lr * 64 + lc;
#pragma unroll
        for (int u = 0; u < 4; ++u) {
            float4 m4 = *(const float4*)(mp + u * 4);
            sm_p[(lc + u * 4 + 0) * 72 + lr] = f2bf(m4.x);
            sm_p[(lc + u * 4 + 1) * 72 + lr] = f2bf(m4.y);
            sm_p[(lc + u * 4 + 2) * 72 + lr] = f2bf(m4.z);
            sm_p[(lc + u * 4 + 3) * 72 + lr] = f2bf(m4.w);
        }
    }
    __syncthreads();

    // num = sq @ mem  (B-operand = mem^T[v][d])
    f32x4 numf[4];
#pragma unroll
    for (int nf = 0; nf < 4; ++nf) numf[nf] = (f32x4)0.f;
#pragma unroll
    for (int ks = 0; ks < 2; ++ks)
#pragma unroll
        for (int nf = 0; nf < 4; ++nf) {
            short8 bm = *(const short8*)&sm_p[(nf * 16 + c16) * 72 + g4 * 8 + ks * 32];
            numf[nf] = __builtin_amdgcn_mfma_f32_16x16x32_bf16(sqh[ks], bm, numf[nf], 0, 0, 0);
        }

    f32x4 o[4];
#pragma unroll
    for (int nf = 0; nf < 4; ++nf) o[nf] = (f32x4)0.f;
    float mrow[4] = {-1e30f, -1e30f, -1e30f, -1e30f};
    float lrow[4] = {0.f, 0.f, 0.f, 0.f};

    for (int kb = 0; kb < 8; ++kb) {
        __syncthreads();
        {   // stage k and V^T (bf16 raw copies)
            const unsigned short* kp = kt + (size_t)(kb * 64 + lr) * 64 + lc;
            *(ushort8*)&sm_k[lr * 72 + lc]     = *(const ushort8*)kp;
            *(ushort8*)&sm_k[lr * 72 + lc + 8] = *(const ushort8*)(kp + 8);
            const unsigned short* vp = vt + (size_t)lr * 512 + kb * 64 + lc;
            *(ushort8*)&sm_v[lr * 72 + lc]     = *(const ushort8*)vp;
            *(ushort8*)&sm_v[lr * 72 + lc + 8] = *(const ushort8*)(vp + 8);
        }
        __syncthreads();

        // scores S = Q @ K^T
        f32x4 s[4];
#pragma unroll
        for (int nf = 0; nf < 4; ++nf) s[nf] = (f32x4)0.f;
#pragma unroll
        for (int ks = 0; ks < 2; ++ks)
#pragma unroll
            for (int nf = 0; nf < 4; ++nf) {
                short8 bk = *(const short8*)&sm_k[(nf * 16 + c16) * 72 + g4 * 8 + ks * 32];
                s[nf] = __builtin_amdgcn_mfma_f32_16x16x32_bf16(qh[ks], bk, s[nf], 0, 0, 0);
            }
#pragma unroll
        for (int nf = 0; nf < 4; ++nf) s[nf] *= 0.125f;

        float corr[4];
#pragma unroll
        for (int r = 0; r < 4; ++r) {
            float mx = fmaxf(fmaxf(s[0][r], s[1][r]), fmaxf(s[2][r], s[3][r]));
            mx = fmaxf(mx, __shfl_xor(mx, 1));
            mx = fmaxf(mx, __shfl_xor(mx, 2));
            mx = fmaxf(mx, __shfl_xor(mx, 4));
            mx = fmaxf(mx, __shfl_xor(mx, 8));
            float mnew = fmaxf(mrow[r], mx);
            corr[r] = __expf(mrow[r] - mnew);
            mrow[r] = mnew;
        }
#pragma unroll
        for (int nf = 0; nf < 4; ++nf)
#pragma unroll
            for (int r = 0; r < 4; ++r)
                s[nf][r] = __expf(s[nf][r] - mrow[r]);
#pragma unroll
        for (int r = 0; r < 4; ++r) {
            float ps = s[0][r] + s[1][r] + s[2][r] + s[3][r];
            ps += __shfl_xor(ps, 1);
            ps += __shfl_xor(ps, 2);
            ps += __shfl_xor(ps, 4);
            ps += __shfl_xor(ps, 8);
            lrow[r] = lrow[r] * corr[r] + ps;
        }
#pragma unroll
        for (int nf = 0; nf < 4; ++nf)
#pragma unroll
            for (int r = 0; r < 4; ++r) o[nf][r] *= corr[r];

        // publish P (C-layout -> A-layout), same-wave rows only: no barrier
#pragma unroll
        for (int nf = 0; nf < 4; ++nf)
#pragma unroll
            for (int r = 0; r < 4; ++r)
                sm_p[(w * 16 + g4 * 4 + r) * 72 + nf * 16 + c16] = f2bf(s[nf][r]);

        // O += P @ V  (B-operand = V^T[v][t])
#pragma unroll
        for (int ks = 0; ks < 2; ++ks) {
            short8 pa = *(const short8*)&sm_p[(w * 16 + c16) * 72 + g4 * 8 + ks * 32];
#pragma unroll
            for (int nf = 0; nf < 4; ++nf) {
                short8 bv = *(const short8*)&sm_v[(nf * 16 + c16) * 72 + g4 * 8 + ks * 32];
                o[nf] = __builtin_amdgcn_mfma_f32_16x16x32_bf16(pa, bv, o[nf], 0, 0, 0);
            }
        }
    }

    __syncthreads();   // staging done — reuse sm_k for att

    float rs[4], invl[4];
#pragma unroll
    for (int r = 0; r < 4; ++r) {
        rs[r]   = __shfl(rowsum, (g4 << 2) + r);
        invl[r] = 1.f / lrow[r];
    }
#pragma unroll
    for (int nf = 0; nf < 4; ++nf) {
        const int col = nf * 16 + c16;
        const float Zc = Zsh[col], gc = gsh[col];
        const float izc = 1.f / Zc;
#pragma unroll
        for (int r = 0; r < 4; ++r) {
            const float adot = o[nf][r] * invl[r];
            const float amem = numf[nf][r] * izc / rs[r];
            const float res  = gc * amem + (1.f - gc) * adot;
            sm_k[(w * 16 + g4 * 4 + r) * 72 + col] = f2bf(res);
        }
    }
    __syncthreads();
    {
        const size_t ob = base + (size_t)(qc * 64 + lr) * 64 + lc;
        *(ushort8*)(ath + ob)     = *(const ushort8*)&sm_k[lr * 72 + lc];
        *(ushort8*)(ath + ob + 8) = *(const ushort8*)&sm_k[lr * 72 + lc + 8];
    }
}

extern "C" void kernel_launch(void* const* d_in, const int* in_sizes, int n_in,
                              void* d_out, int out_size, void* d_ws, size_t ws_size,
                              hipStream_t stream) {
    const float* x     = (const float*)d_in[0];
    const float* Wq    = (const float*)d_in[1];
    const float* Wk    = (const float*)d_in[2];
    const float* Wv    = (const float*)d_in[3];
    const float* Wout  = (const float*)d_in[4];
    const float* betas = (const float*)d_in[5];
    float* out = (float*)d_out;
    (void)d_ws; (void)ws_size;

    float *M, *z;
    unsigned short *qb, *kb, *vb, *xh, *wqkv, *vt, *ath, *woh;
    hipGetSymbolAddress((void**)&qb,   HIP_SYMBOL(g_qb));
    hipGetSymbolAddress((void**)&kb,   HIP_SYMBOL(g_kb));
    hipGetSymbolAddress((void**)&vb,   HIP_SYMBOL(g_vb));
    hipGetSymbolAddress((void**)&xh,   HIP_SYMBOL(g_xh));
    hipGetSymbolAddress((void**)&wqkv, HIP_SYMBOL(g_wqkv));
    hipGetSymbolAddress((void**)&vt,   HIP_SYMBOL(g_vt));
    hipGetSymbolAddress((void**)&ath,  HIP_SYMBOL(g_ath));
    hipGetSymbolAddress((void**)&woh,  HIP_SYMBOL(g_woh));
    hipGetSymbolAddress((void**)&M,    HIP_SYMBOL(g_M));
    hipGetSymbolAddress((void**)&z,    HIP_SYMBOL(g_z));

    const int nX = (int)NPROJ, nW = (int)NW;
    cast_bf16<<<nX / 1024, 256, 0, stream>>>(x, xh, nX);
    cast_bf16<<<nW / 1024, 256, 0, stream>>>(Wq, wqkv, nW);
    cast_bf16<<<nW / 1024, 256, 0, stream>>>(Wk, wqkv + NW, nW);
    cast_bf16<<<nW / 1024, 256, 0, stream>>>(Wv, wqkv + 2 * NW, nW);
    cast_bf16<<<nW / 1024, 256, 0, stream>>>(Wout, woh, nW);

    gemm_qkv<<<dim3(3 * D_ / 128, BT_ / 128), 256, 0, stream>>>(xh, wqkv, qb, kb, vb);
    seg_stats<<<B_ * H_ * NSEG_, 256, 0, stream>>>(kb, vb, M, z, vt);
    prefix_scan<<<B_ * H_, 256, 0, stream>>>(M, z);
    attn_mfma<<<B_ * H_ * NSEG_ * 8, 256, 0, stream>>>(qb, kb, vt, M, z, betas, ath);
    gemm_bt_bf16<<<dim3(D_ / 128, BT_ / 128), 256, 0, stream>>>(ath, woh, out, BT_, D_, D_);
}